// Round 6
// baseline (147.655 us; speedup 1.0000x reference)
//
#include <hip/hip_runtime.h>

#define BB 4
#define NV 4096
#define BN (BB * NV)
#define CC 64
#define HH 376
#define WW 1240
#define HW (HH * WW)
#define LDT 72          // P LDS row stride (ushorts)
#define NSPLIT 4
#define TILES 16        // 16 tiles x 64 keys = 1024 keys per split
#define QSCALE 0.1803368801111244f  // (1/8) * log2(e)

typedef __bf16 bf16x8 __attribute__((ext_vector_type(8)));
typedef __bf16 bf16x4 __attribute__((ext_vector_type(4)));
typedef float  f32x4  __attribute__((ext_vector_type(4)));

// ---------------- prep: gather + Q(3)/K(3)/V projections + passthrough ----------------
// 256 threads/block, 32 voxels/block, 8 threads per voxel; Wqk3 computed in-block.
__global__ __launch_bounds__(256) void kprep(
    const float* __restrict__ vfeat, const float* __restrict__ v3d,
    const float* __restrict__ img, const int* __restrict__ vx,
    const int* __restrict__ vy, const float* __restrict__ qw,
    const float* __restrict__ qb, const float* __restrict__ kwm,
    const float* __restrict__ vw, const float* __restrict__ vb,
    float* __restrict__ out, unsigned short* __restrict__ Qp,
    unsigned short* __restrict__ K8, unsigned short* __restrict__ VTb) {
  __shared__ float VfS[32][68];
  __shared__ float CamS[32][68];
  __shared__ float WqkS[64][4];
  __shared__ float bqkS[4];
  const int tid = threadIdx.x;
  const int vl = tid >> 3;   // voxel-local 0..31
  const int p = tid & 7;     // slice 0..7
  const int gv = blockIdx.x * 32 + vl;
  const int b = gv >> 12, n = gv & (NV - 1);
  const size_t row = (size_t)b * NV + n;

  // Wqk3[j][d] = sum_c qw[c][j]*kw[c][d]; bqk3[d] = sum_c qb[c]*kw[c][d]
  if (tid < 192) {
    int j = tid / 3, d = tid - j * 3;
    float a = 0.f;
    for (int c = 0; c < CC; ++c) a = fmaf(qw[c * CC + j], kwm[c * 3 + d], a);
    WqkS[j][d] = a;
  } else if (tid < 195) {
    int d = tid - 192;
    float a = 0.f;
    for (int c = 0; c < CC; ++c) a = fmaf(qb[c], kwm[c * 3 + d], a);
    bqkS[d] = a;
  }

  // vfeat slice: passthrough + LDS stash
  {
    const float4* vf4 = (const float4*)(vfeat + row * CC) + p * 2;
    float4* o4 = (float4*)(out + row * 128) + p * 2;
    float4* s4 = (float4*)&VfS[vl][p * 8];
#pragma unroll
    for (int i = 0; i < 2; ++i) { float4 t = vf4[i]; o4[i] = t; s4[i] = t; }
  }

  // camera gather, channels [8p, 8p+8)
  {
    int x = vx[row], y = vy[row];
    bool valid = (x >= 0) & (x < WW) & (y >= 0) & (y < HH);
    int xs = valid ? x : 0, ys = valid ? y : 0;
    const float* ib = img + ((size_t)b * CC + p * 8) * (size_t)HW + (size_t)ys * WW + xs;
#pragma unroll
    for (int i = 0; i < 8; ++i) {
      float cv = ib[(size_t)i * HW];
      CamS[vl][p * 8 + i] = valid ? cv : 0.f;
    }
  }

  // K8: raw 3d coords bf16, padded to 8
  if (p == 1) {
    float c0 = v3d[row * 3 + 0], c1 = v3d[row * 3 + 1], c2 = v3d[row * 3 + 2];
    bf16x8 kp = {(__bf16)c0, (__bf16)c1, (__bf16)c2, (__bf16)0.f,
                 (__bf16)0.f, (__bf16)0.f, (__bf16)0.f, (__bf16)0.f};
    *(bf16x8*)(K8 + row * 8) = kp;
  }
  __syncthreads();

  // V projection, output channels [8p, 8p+8), store transposed bf16
  {
    f32x4 vr[16];
#pragma unroll
    for (int i = 0; i < 16; ++i) vr[i] = *(const f32x4*)&VfS[vl][i * 4];
#pragma unroll
    for (int cc = 0; cc < 8; ++cc) {
      int c = p * 8 + cc;
      const float4* w4 = (const float4*)(vw + c * CC);
      float acc = vb[c];
#pragma unroll
      for (int j = 0; j < 16; ++j) {
        float4 w = w4[j];
        acc = fmaf(vr[j][0], w.x, fmaf(vr[j][1], w.y, fmaf(vr[j][2], w.z, fmaf(vr[j][3], w.w, acc))));
      }
      ((__bf16*)VTb)[((size_t)b * CC + c) * NV + n] = (__bf16)acc;
    }
  }

  // Qp: qp3 = QSCALE*(cam @ Wqk3 + bqk3), bf16, padded to 8
  if (p == 0) {
    float q0 = bqkS[0], q1 = bqkS[1], q2 = bqkS[2];
#pragma unroll 8
    for (int j = 0; j < CC; ++j) {
      float c = CamS[vl][j];
      q0 = fmaf(c, WqkS[j][0], q0);
      q1 = fmaf(c, WqkS[j][1], q1);
      q2 = fmaf(c, WqkS[j][2], q2);
    }
    bf16x8 qp = {(__bf16)(q0 * QSCALE), (__bf16)(q1 * QSCALE), (__bf16)(q2 * QSCALE),
                 (__bf16)0.f, (__bf16)0.f, (__bf16)0.f, (__bf16)0.f, (__bf16)0.f};
    *(bf16x8*)(Qp + row * 8) = qp;
  }
}

// ---------------- flash attention, split-K x4, direct-L2 K/V, no block barriers ----------------
// grid 1024 = 4 batch x 4 splits x 64 q-chunks; 4 waves/block; 4 blocks/CU.
__global__ __launch_bounds__(256, 4) void kattn(const unsigned short* __restrict__ Qp,
                                                const unsigned short* __restrict__ K8,
                                                const unsigned short* __restrict__ VTb,
                                                unsigned short* __restrict__ Opb,
                                                float* __restrict__ ml) {
  __shared__ unsigned short Ps[4][16 * LDT];

  const int bid = blockIdx.x;
  const int xcd = bid & 7;
  const int idx = bid >> 3;                // 0..127
  const int combo = xcd * 2 + (idx >> 6);  // 0..15 -> (b, split)
  const int qc = idx & 63;
  const int b = combo >> 2;
  const int sp = combo & 3;
  const int q0 = qc * 64;
  const int key0 = sp * (TILES * 64);

  const int tid = threadIdx.x;
  const int wid = tid >> 6;
  const int lane = tid & 63;
  const int lq = lane & 15;
  const int lg = lane >> 4;
  const bool ld0 = (lg == 0);

  const bf16x8 bz = {(__bf16)0.f, (__bf16)0.f, (__bf16)0.f, (__bf16)0.f,
                     (__bf16)0.f, (__bf16)0.f, (__bf16)0.f, (__bf16)0.f};

  const bf16x8 qf = ld0 ? *(const bf16x8*)(Qp + ((size_t)b * NV + q0 + wid * 16 + lq) * 8) : bz;

  const f32x4 vzero = {0.f, 0.f, 0.f, 0.f};
  float m_run = -1e30f, l_run = 0.f;
  f32x4 oacc[4];
#pragma unroll
  for (int t = 0; t < 4; ++t) oacc[t] = vzero;

  const unsigned short* kgb = K8 + (size_t)b * NV * 8;
  const unsigned short* vgb = VTb + (size_t)b * CC * NV;

  for (int tt = 0; tt < TILES; ++tt) {
    const int kb0 = key0 + tt * 64;

    // S^T = K . Q^T (log2 domain; k>=8 is zero on both operands)
    f32x4 s[4];
#pragma unroll
    for (int t = 0; t < 4; ++t) {
      bf16x8 ka = ld0 ? *(const bf16x8*)(kgb + (size_t)(kb0 + t * 16 + lq) * 8) : bz;
      s[t] = __builtin_amdgcn_mfma_f32_16x16x32_bf16(ka, qf, vzero, 0, 0, 0);
    }

    // tile max
    float t0m = fmaxf(fmaxf(s[0][0], s[0][1]), fmaxf(s[0][2], s[0][3]));
    float t1m = fmaxf(fmaxf(s[1][0], s[1][1]), fmaxf(s[1][2], s[1][3]));
    float t2m = fmaxf(fmaxf(s[2][0], s[2][1]), fmaxf(s[2][2], s[2][3]));
    float t3m = fmaxf(fmaxf(s[3][0], s[3][1]), fmaxf(s[3][2], s[3][3]));
    float tmax = fmaxf(fmaxf(t0m, t1m), fmaxf(t2m, t3m));
    tmax = fmaxf(tmax, __shfl_xor(tmax, 16));
    tmax = fmaxf(tmax, __shfl_xor(tmax, 32));

    // defer-max: rescale only when some query's max grew by >8 (log2 domain)
    if (!__all(tmax <= m_run + 8.f)) {
      float m_new = fmaxf(m_run, tmax);
      float sc = __builtin_amdgcn_exp2f(m_run - m_new);
      l_run *= sc;
      m_run = m_new;
#pragma unroll
      for (int r = 0; r < 4; ++r) {
        float scr = __shfl(sc, lg * 4 + r);
#pragma unroll
        for (int t = 0; t < 4; ++t) oacc[t][r] *= scr;
      }
    }

    float psum = 0.f;
#pragma unroll
    for (int t = 0; t < 4; ++t) {
      float p0 = __builtin_amdgcn_exp2f(s[t][0] - m_run);
      float p1 = __builtin_amdgcn_exp2f(s[t][1] - m_run);
      float p2 = __builtin_amdgcn_exp2f(s[t][2] - m_run);
      float p3 = __builtin_amdgcn_exp2f(s[t][3] - m_run);
      psum += (p0 + p1) + (p2 + p3);
      bf16x4 pk;
      pk[0] = (__bf16)p0; pk[1] = (__bf16)p1; pk[2] = (__bf16)p2; pk[3] = (__bf16)p3;
      *(bf16x4*)&Ps[wid][lq * LDT + t * 16 + lg * 4] = pk;
    }
    psum += __shfl_xor(psum, 16);
    psum += __shfl_xor(psum, 32);
    l_run += psum;

    // O += P . V  (P from per-wave LDS; V fragments direct from L2)
#pragma unroll
    for (int ks = 0; ks < 2; ++ks) {
      bf16x8 pa = *(const bf16x8*)&Ps[wid][lq * LDT + ks * 32 + lg * 8];
#pragma unroll
      for (int t = 0; t < 4; ++t) {
        bf16x8 vbf = *(const bf16x8*)(vgb + (size_t)(t * 16 + lq) * NV + kb0 + ks * 32 + lg * 8);
        oacc[t] = __builtin_amdgcn_mfma_f32_16x16x32_bf16(pa, vbf, oacc[t], 0, 0, 0);
      }
    }
  }

  // write unnormalized partial O (bf16) and (m,l)
  const size_t obase = (size_t)sp * BN + (size_t)b * NV + q0 + wid * 16;
#pragma unroll
  for (int r = 0; r < 4; ++r) {
    __bf16* op = (__bf16*)Opb + (obase + lg * 4 + r) * CC + lq;
#pragma unroll
    for (int t = 0; t < 4; ++t) op[t * 16] = (__bf16)oacc[t][r];
  }
  if (lg == 0) {
    float2 t2; t2.x = m_run; t2.y = l_run;
    ((float2*)ml)[obase + lq] = t2;
  }
}

// ---------------- merge 4 partials + fused epilogue (W2 computed in-block) ----------------
__global__ __launch_bounds__(256) void kmerge(const unsigned short* __restrict__ Opb,
                                              const float* __restrict__ ml,
                                              const float* __restrict__ ow,
                                              const float* __restrict__ ob,
                                              const float* __restrict__ fc,
                                              float* __restrict__ out) {
  __shared__ unsigned short W2s[64 * LDT];
  __shared__ float b2s[64];
  const int tid = threadIdx.x;
  const int wid = tid >> 6;
  const int lane = tid & 63;
  const int lq = lane & 15;
  const int lg = lane >> 4;

  // W2[i][j] = sum_k fc[i][k]*ow[k][j]; thread: i = tid>>2, j in [16*(tid&3), +16)
  {
    const int i = tid >> 2;
    const int jb = (tid & 3) * 16;
    float acc[16];
#pragma unroll
    for (int e = 0; e < 16; ++e) acc[e] = 0.f;
    for (int k = 0; k < CC; ++k) {
      float f = fc[i * CC + k];
      const float4* o4 = (const float4*)(ow + k * CC + jb);
#pragma unroll
      for (int e4 = 0; e4 < 4; ++e4) {
        float4 o = o4[e4];
        acc[e4 * 4 + 0] = fmaf(f, o.x, acc[e4 * 4 + 0]);
        acc[e4 * 4 + 1] = fmaf(f, o.y, acc[e4 * 4 + 1]);
        acc[e4 * 4 + 2] = fmaf(f, o.z, acc[e4 * 4 + 2]);
        acc[e4 * 4 + 3] = fmaf(f, o.w, acc[e4 * 4 + 3]);
      }
    }
    __bf16* wrow = (__bf16*)&W2s[i * LDT + jb];
#pragma unroll
    for (int e = 0; e < 16; ++e) wrow[e] = (__bf16)acc[e];
    if (tid < CC) {
      float a = 0.f;
      for (int k = 0; k < CC; ++k) a = fmaf(fc[tid * CC + k], ob[k], a);
      b2s[tid] = a;
    }
  }
  __syncthreads();

  const int row = blockIdx.x * 64 + wid * 16 + lq;

  float mv[NSPLIT], lv[NSPLIT], w[NSPLIT];
#pragma unroll
  for (int s = 0; s < NSPLIT; ++s) {
    float2 t = ((const float2*)ml)[(size_t)s * BN + row];
    mv[s] = t.x; lv[s] = t.y;
  }
  float mstar = fmaxf(fmaxf(mv[0], mv[1]), fmaxf(mv[2], mv[3]));
  float lstar = 0.f;
#pragma unroll
  for (int s = 0; s < NSPLIT; ++s) {
    w[s] = __builtin_amdgcn_exp2f(mv[s] - mstar);
    lstar = fmaf(w[s], lv[s], lstar);
  }

  float ctx[16];
#pragma unroll
  for (int j = 0; j < 16; ++j) ctx[j] = 0.f;
#pragma unroll
  for (int s = 0; s < NSPLIT; ++s) {
    const __bf16* oprow = (const __bf16*)Opb + ((size_t)s * BN + row) * CC;
    bf16x8 a0 = *(const bf16x8*)(oprow + lg * 8);
    bf16x8 a1 = *(const bf16x8*)(oprow + 32 + lg * 8);
    float ws_ = w[s];
#pragma unroll
    for (int j = 0; j < 8; ++j) {
      ctx[j] = fmaf(ws_, (float)a0[j], ctx[j]);
      ctx[8 + j] = fmaf(ws_, (float)a1[j], ctx[8 + j]);
    }
  }
  float inv = 1.f / lstar;
  bf16x8 cb0, cb1;
#pragma unroll
  for (int j = 0; j < 8; ++j) {
    cb0[j] = (__bf16)(ctx[j] * inv);
    cb1[j] = (__bf16)(ctx[8 + j] * inv);
  }

  const f32x4 vzero = {0.f, 0.f, 0.f, 0.f};
  float* orow = out + (size_t)row * 128 + 64;
#pragma unroll
  for (int t2 = 0; t2 < 4; ++t2) {
    bf16x8 wa0 = *(const bf16x8*)&W2s[(t2 * 16 + lq) * LDT + lg * 8];
    bf16x8 wa1 = *(const bf16x8*)&W2s[(t2 * 16 + lq) * LDT + 32 + lg * 8];
    f32x4 r2 = vzero;
    r2 = __builtin_amdgcn_mfma_f32_16x16x32_bf16(wa0, cb0, r2, 0, 0, 0);
    r2 = __builtin_amdgcn_mfma_f32_16x16x32_bf16(wa1, cb1, r2, 0, 0, 0);
    float4 o;
    o.x = fmaxf(r2[0] + b2s[t2 * 16 + lg * 4 + 0], 0.f);
    o.y = fmaxf(r2[1] + b2s[t2 * 16 + lg * 4 + 1], 0.f);
    o.z = fmaxf(r2[2] + b2s[t2 * 16 + lg * 4 + 2], 0.f);
    o.w = fmaxf(r2[3] + b2s[t2 * 16 + lg * 4 + 3], 0.f);
    *(float4*)(orow + t2 * 16 + lg * 4) = o;
  }
}

extern "C" void kernel_launch(void* const* d_in, const int* in_sizes, int n_in,
                              void* d_out, int out_size, void* d_ws, size_t ws_size,
                              hipStream_t stream) {
  const float* vfeat = (const float*)d_in[0];
  const float* v3d = (const float*)d_in[1];
  const float* img = (const float*)d_in[2];
  const int* vx = (const int*)d_in[3];
  const int* vy = (const int*)d_in[4];
  const float* qw = (const float*)d_in[5];
  const float* qb = (const float*)d_in[6];
  const float* kwm = (const float*)d_in[7];
  // d_in[8] = k_b: cancels in softmax
  const float* vw = (const float*)d_in[9];
  const float* vb = (const float*)d_in[10];
  const float* ow = (const float*)d_in[11];
  const float* ob = (const float*)d_in[12];
  const float* fc = (const float*)d_in[13];
  float* out = (float*)d_out;

  char* ws = (char*)d_ws;
  unsigned short* Qp = (unsigned short*)(ws);              // 256 KB
  unsigned short* K8 = (unsigned short*)(ws + 262144);     // 256 KB
  unsigned short* VTb = (unsigned short*)(ws + 524288);    // 2 MB
  unsigned short* Opb = (unsigned short*)(ws + 2621440);   // 8 MB
  float* ml = (float*)(ws + 11010048);                     // 512 KB

  kprep<<<512, 256, 0, stream>>>(vfeat, v3d, img, vx, vy, qw, qb, kwm, vw, vb,
                                 out, Qp, K8, VTb);
  kattn<<<1024, 256, 0, stream>>>(Qp, K8, VTb, Opb, ml);
  kmerge<<<256, 256, 0, stream>>>(Opb, ml, ow, ob, fc, out);
}

// Round 7
// 134.639 us; speedup vs baseline: 1.0967x; 1.0967x over previous
//
#include <hip/hip_runtime.h>

#define BB 4
#define NV 4096
#define BN (BB * NV)
#define CC 64
#define HH 376
#define WW 1240
#define HW (HH * WW)
#define LDT 72          // P/V LDS row stride (ushorts)
#define NSPLIT 4
#define TILES 16        // 16 tiles x 64 keys = 1024 keys per split
#define QSCALE 0.1803368801111244f  // (1/8) * log2(e)

typedef __bf16 bf16x8 __attribute__((ext_vector_type(8)));
typedef __bf16 bf16x4 __attribute__((ext_vector_type(4)));
typedef float  f32x4  __attribute__((ext_vector_type(4)));

// ---------------- prep: gather + Q(3)/K(3)/V projections + passthrough ----------------
__global__ __launch_bounds__(256) void kprep(
    const float* __restrict__ vfeat, const float* __restrict__ v3d,
    const float* __restrict__ img, const int* __restrict__ vx,
    const int* __restrict__ vy, const float* __restrict__ qw,
    const float* __restrict__ qb, const float* __restrict__ kwm,
    const float* __restrict__ vw, const float* __restrict__ vb,
    float* __restrict__ out, unsigned short* __restrict__ Qp,
    unsigned short* __restrict__ K8, unsigned short* __restrict__ VTb) {
  __shared__ float VfS[32][68];
  __shared__ float CamS[32][68];
  __shared__ float WqkS[64][4];
  __shared__ float bqkS[4];
  const int tid = threadIdx.x;
  const int vl = tid >> 3;   // voxel-local 0..31
  const int p = tid & 7;     // slice 0..7
  const int gv = blockIdx.x * 32 + vl;
  const int b = gv >> 12, n = gv & (NV - 1);
  const size_t row = (size_t)b * NV + n;

  // Wqk3[j][d] = sum_c qw[c][j]*kw[c][d]; bqk3[d] = sum_c qb[c]*kw[c][d]
  if (tid < 192) {
    int j = tid / 3, d = tid - j * 3;
    float a = 0.f;
    for (int c = 0; c < CC; ++c) a = fmaf(qw[c * CC + j], kwm[c * 3 + d], a);
    WqkS[j][d] = a;
  } else if (tid < 195) {
    int d = tid - 192;
    float a = 0.f;
    for (int c = 0; c < CC; ++c) a = fmaf(qb[c], kwm[c * 3 + d], a);
    bqkS[d] = a;
  }

  // vfeat slice: passthrough + LDS stash
  {
    const float4* vf4 = (const float4*)(vfeat + row * CC) + p * 2;
    float4* o4 = (float4*)(out + row * 128) + p * 2;
    float4* s4 = (float4*)&VfS[vl][p * 8];
#pragma unroll
    for (int i = 0; i < 2; ++i) { float4 t = vf4[i]; o4[i] = t; s4[i] = t; }
  }

  // camera gather, channels [8p, 8p+8)
  {
    int x = vx[row], y = vy[row];
    bool valid = (x >= 0) & (x < WW) & (y >= 0) & (y < HH);
    int xs = valid ? x : 0, ys = valid ? y : 0;
    const float* ib = img + ((size_t)b * CC + p * 8) * (size_t)HW + (size_t)ys * WW + xs;
#pragma unroll
    for (int i = 0; i < 8; ++i) {
      float cv = ib[(size_t)i * HW];
      CamS[vl][p * 8 + i] = valid ? cv : 0.f;
    }
  }

  // K8: raw 3d coords bf16, padded to 8
  if (p == 1) {
    float c0 = v3d[row * 3 + 0], c1 = v3d[row * 3 + 1], c2 = v3d[row * 3 + 2];
    bf16x8 kp = {(__bf16)c0, (__bf16)c1, (__bf16)c2, (__bf16)0.f,
                 (__bf16)0.f, (__bf16)0.f, (__bf16)0.f, (__bf16)0.f};
    *(bf16x8*)(K8 + row * 8) = kp;
  }
  __syncthreads();

  // V projection, output channels [8p, 8p+8), store transposed bf16
  {
    f32x4 vr[16];
#pragma unroll
    for (int i = 0; i < 16; ++i) vr[i] = *(const f32x4*)&VfS[vl][i * 4];
#pragma unroll
    for (int cc = 0; cc < 8; ++cc) {
      int c = p * 8 + cc;
      const float4* w4 = (const float4*)(vw + c * CC);
      float acc = vb[c];
#pragma unroll
      for (int j = 0; j < 16; ++j) {
        float4 w = w4[j];
        acc = fmaf(vr[j][0], w.x, fmaf(vr[j][1], w.y, fmaf(vr[j][2], w.z, fmaf(vr[j][3], w.w, acc))));
      }
      ((__bf16*)VTb)[((size_t)b * CC + c) * NV + n] = (__bf16)acc;
    }
  }

  // Qp: qp3 = QSCALE*(cam @ Wqk3 + bqk3), bf16, padded to 8
  if (p == 0) {
    float q0 = bqkS[0], q1 = bqkS[1], q2 = bqkS[2];
#pragma unroll 8
    for (int j = 0; j < CC; ++j) {
      float c = CamS[vl][j];
      q0 = fmaf(c, WqkS[j][0], q0);
      q1 = fmaf(c, WqkS[j][1], q1);
      q2 = fmaf(c, WqkS[j][2], q2);
    }
    bf16x8 qp = {(__bf16)(q0 * QSCALE), (__bf16)(q1 * QSCALE), (__bf16)(q2 * QSCALE),
                 (__bf16)0.f, (__bf16)0.f, (__bf16)0.f, (__bf16)0.f, (__bf16)0.f};
    *(bf16x8*)(Qp + row * 8) = qp;
  }
}

// ---------------- flash attention, split-K x4, fixed-M0 softmax ----------------
// grid 1024 = 4 batch x 4 splits x 64 q-chunks; 4 waves/block; 4 blocks/CU.
__global__ __launch_bounds__(256, 4) void kattn(const unsigned short* __restrict__ Qp,
                                                const unsigned short* __restrict__ K8,
                                                const unsigned short* __restrict__ VTb,
                                                unsigned short* __restrict__ Opb,
                                                float* __restrict__ ml) {
  __shared__ unsigned short Vs[2][64 * LDT];
  __shared__ unsigned short Ps[4][16 * LDT];

  const int bid = blockIdx.x;
  const int xcd = bid & 7;
  const int idx = bid >> 3;                // 0..127
  const int combo = xcd * 2 + (idx >> 6);  // 0..15 -> (b, split)
  const int qc = idx & 63;
  const int b = combo >> 2;
  const int sp = combo & 3;
  const int q0 = qc * 64;
  const int key0 = sp * (TILES * 64);

  const int tid = threadIdx.x;
  const int wid = tid >> 6;
  const int lane = tid & 63;
  const int lq = lane & 15;
  const int lg = lane >> 4;
  const bool ld0 = (lg == 0);

  const int srow = tid >> 2;         // 0..63
  const int scol = (tid & 3) * 16;   // V slot (2x uint4)

  const bf16x8 bz = {(__bf16)0.f, (__bf16)0.f, (__bf16)0.f, (__bf16)0.f,
                     (__bf16)0.f, (__bf16)0.f, (__bf16)0.f, (__bf16)0.f};
  const bf16x8 qf = ld0 ? *(const bf16x8*)(Qp + ((size_t)b * NV + q0 + wid * 16 + lq) * 8) : bz;
  const f32x4 cinit = {-16.f, -16.f, -16.f, -16.f};  // fixed M0 folded into MFMA C

  float l_run = 0.f;
  f32x4 oacc[4];
#pragma unroll
  for (int t = 0; t < 4; ++t) oacc[t] = {0.f, 0.f, 0.f, 0.f};

  const unsigned short* kgb = K8 + (size_t)b * NV * 8;
  const unsigned short* vgb = VTb + (size_t)b * CC * NV;

  uint4 vr0, vr1;
  bf16x8 ka0, ka1, ka2, ka3;
  {  // prologue: stage V tile 0, load K frags tile 0
    const uint4* vsrc = (const uint4*)(vgb + (size_t)srow * NV + key0 + scol);
    vr0 = vsrc[0]; vr1 = vsrc[1];
    uint4* vdst = (uint4*)&Vs[0][srow * LDT + scol];
    vdst[0] = vr0; vdst[1] = vr1;
    ka0 = ld0 ? *(const bf16x8*)(kgb + (size_t)(key0 + 0 * 16 + lq) * 8) : bz;
    ka1 = ld0 ? *(const bf16x8*)(kgb + (size_t)(key0 + 1 * 16 + lq) * 8) : bz;
    ka2 = ld0 ? *(const bf16x8*)(kgb + (size_t)(key0 + 2 * 16 + lq) * 8) : bz;
    ka3 = ld0 ? *(const bf16x8*)(kgb + (size_t)(key0 + 3 * 16 + lq) * 8) : bz;
  }
  __syncthreads();

  int cur = 0;
#pragma unroll
  for (int tt = 0; tt < TILES; ++tt) {
    // S^T = K . Q^T - 16 (log2 domain)
    f32x4 s[4];
    s[0] = __builtin_amdgcn_mfma_f32_16x16x32_bf16(ka0, qf, cinit, 0, 0, 0);
    s[1] = __builtin_amdgcn_mfma_f32_16x16x32_bf16(ka1, qf, cinit, 0, 0, 0);
    s[2] = __builtin_amdgcn_mfma_f32_16x16x32_bf16(ka2, qf, cinit, 0, 0, 0);
    s[3] = __builtin_amdgcn_mfma_f32_16x16x32_bf16(ka3, qf, cinit, 0, 0, 0);

    // prefetch next tile (K frags + V regs) — latency hides under softmax+PV
    bf16x8 kn0 = bz, kn1 = bz, kn2 = bz, kn3 = bz;
    uint4 vn0 = {0, 0, 0, 0}, vn1 = {0, 0, 0, 0};
    if (tt + 1 < TILES) {
      int k0 = key0 + (tt + 1) * 64;
      kn0 = ld0 ? *(const bf16x8*)(kgb + (size_t)(k0 + 0 * 16 + lq) * 8) : bz;
      kn1 = ld0 ? *(const bf16x8*)(kgb + (size_t)(k0 + 1 * 16 + lq) * 8) : bz;
      kn2 = ld0 ? *(const bf16x8*)(kgb + (size_t)(k0 + 2 * 16 + lq) * 8) : bz;
      kn3 = ld0 ? *(const bf16x8*)(kgb + (size_t)(k0 + 3 * 16 + lq) * 8) : bz;
      const uint4* vsrc = (const uint4*)(vgb + (size_t)srow * NV + k0 + scol);
      vn0 = vsrc[0]; vn1 = vsrc[1];
    }

    // p = exp2(s); accumulate lane-partial l (no max tracking, no rescale)
#pragma unroll
    for (int t = 0; t < 4; ++t) {
      float p0 = __builtin_amdgcn_exp2f(s[t][0]);
      float p1 = __builtin_amdgcn_exp2f(s[t][1]);
      float p2 = __builtin_amdgcn_exp2f(s[t][2]);
      float p3 = __builtin_amdgcn_exp2f(s[t][3]);
      l_run += (p0 + p1) + (p2 + p3);
      bf16x4 pk;
      pk[0] = (__bf16)p0; pk[1] = (__bf16)p1; pk[2] = (__bf16)p2; pk[3] = (__bf16)p3;
      *(bf16x4*)&Ps[wid][lq * LDT + t * 16 + lg * 4] = pk;
    }

    // O += P . V
#pragma unroll
    for (int ks = 0; ks < 2; ++ks) {
      bf16x8 pa = *(const bf16x8*)&Ps[wid][lq * LDT + ks * 32 + lg * 8];
#pragma unroll
      for (int t = 0; t < 4; ++t) {
        bf16x8 vbf = *(const bf16x8*)&Vs[cur][(t * 16 + lq) * LDT + ks * 32 + lg * 8];
        oacc[t] = __builtin_amdgcn_mfma_f32_16x16x32_bf16(pa, vbf, oacc[t], 0, 0, 0);
      }
    }

    if (tt + 1 < TILES) {
      uint4* vdst = (uint4*)&Vs[cur ^ 1][srow * LDT + scol];
      vdst[0] = vn0; vdst[1] = vn1;
    }
    __syncthreads();
    cur ^= 1;
    ka0 = kn0; ka1 = kn1; ka2 = kn2; ka3 = kn3;
  }

  // final l reduction across the 4 lanes sharing query lq
  l_run += __shfl_xor(l_run, 16);
  l_run += __shfl_xor(l_run, 32);

  // write unnormalized partial O (bf16) and l
  const size_t obase = (size_t)sp * BN + (size_t)b * NV + q0 + wid * 16;
#pragma unroll
  for (int r = 0; r < 4; ++r) {
    __bf16* op = (__bf16*)Opb + (obase + lg * 4 + r) * CC + lq;
#pragma unroll
    for (int t = 0; t < 4; ++t) op[t * 16] = (__bf16)oacc[t][r];
  }
  if (ld0) ml[obase + lq] = l_run;
}

// ---------------- merge 4 partials (plain sum) + fused epilogue ----------------
__global__ __launch_bounds__(256) void kmerge(const unsigned short* __restrict__ Opb,
                                              const float* __restrict__ ml,
                                              const float* __restrict__ ow,
                                              const float* __restrict__ ob,
                                              const float* __restrict__ fc,
                                              float* __restrict__ out) {
  __shared__ unsigned short W2s[64 * LDT];
  __shared__ float b2s[64];
  const int tid = threadIdx.x;
  const int wid = tid >> 6;
  const int lane = tid & 63;
  const int lq = lane & 15;
  const int lg = lane >> 4;

  // W2[i][j] = sum_k fc[i][k]*ow[k][j]
  {
    const int i = tid >> 2;
    const int jb = (tid & 3) * 16;
    float acc[16];
#pragma unroll
    for (int e = 0; e < 16; ++e) acc[e] = 0.f;
    for (int k = 0; k < CC; ++k) {
      float f = fc[i * CC + k];
      const float4* o4 = (const float4*)(ow + k * CC + jb);
#pragma unroll
      for (int e4 = 0; e4 < 4; ++e4) {
        float4 o = o4[e4];
        acc[e4 * 4 + 0] = fmaf(f, o.x, acc[e4 * 4 + 0]);
        acc[e4 * 4 + 1] = fmaf(f, o.y, acc[e4 * 4 + 1]);
        acc[e4 * 4 + 2] = fmaf(f, o.z, acc[e4 * 4 + 2]);
        acc[e4 * 4 + 3] = fmaf(f, o.w, acc[e4 * 4 + 3]);
      }
    }
    __bf16* wrow = (__bf16*)&W2s[i * LDT + jb];
#pragma unroll
    for (int e = 0; e < 16; ++e) wrow[e] = (__bf16)acc[e];
    if (tid < CC) {
      float a = 0.f;
      for (int k = 0; k < CC; ++k) a = fmaf(fc[tid * CC + k], ob[k], a);
      b2s[tid] = a;
    }
  }
  __syncthreads();

  const int row = blockIdx.x * 64 + wid * 16 + lq;

  float lstar = 0.f;
#pragma unroll
  for (int s = 0; s < NSPLIT; ++s) lstar += ml[(size_t)s * BN + row];

  float ctx[16];
#pragma unroll
  for (int j = 0; j < 16; ++j) ctx[j] = 0.f;
#pragma unroll
  for (int s = 0; s < NSPLIT; ++s) {
    const __bf16* oprow = (const __bf16*)Opb + ((size_t)s * BN + row) * CC;
    bf16x8 a0 = *(const bf16x8*)(oprow + lg * 8);
    bf16x8 a1 = *(const bf16x8*)(oprow + 32 + lg * 8);
#pragma unroll
    for (int j = 0; j < 8; ++j) {
      ctx[j] += (float)a0[j];
      ctx[8 + j] += (float)a1[j];
    }
  }
  float inv = 1.f / lstar;
  bf16x8 cb0, cb1;
#pragma unroll
  for (int j = 0; j < 8; ++j) {
    cb0[j] = (__bf16)(ctx[j] * inv);
    cb1[j] = (__bf16)(ctx[8 + j] * inv);
  }

  const f32x4 vzero = {0.f, 0.f, 0.f, 0.f};
  float* orow = out + (size_t)row * 128 + 64;
#pragma unroll
  for (int t2 = 0; t2 < 4; ++t2) {
    bf16x8 wa0 = *(const bf16x8*)&W2s[(t2 * 16 + lq) * LDT + lg * 8];
    bf16x8 wa1 = *(const bf16x8*)&W2s[(t2 * 16 + lq) * LDT + 32 + lg * 8];
    f32x4 r2 = vzero;
    r2 = __builtin_amdgcn_mfma_f32_16x16x32_bf16(wa0, cb0, r2, 0, 0, 0);
    r2 = __builtin_amdgcn_mfma_f32_16x16x32_bf16(wa1, cb1, r2, 0, 0, 0);
    float4 o;
    o.x = fmaxf(r2[0] + b2s[t2 * 16 + lg * 4 + 0], 0.f);
    o.y = fmaxf(r2[1] + b2s[t2 * 16 + lg * 4 + 1], 0.f);
    o.z = fmaxf(r2[2] + b2s[t2 * 16 + lg * 4 + 2], 0.f);
    o.w = fmaxf(r2[3] + b2s[t2 * 16 + lg * 4 + 3], 0.f);
    *(float4*)(orow + t2 * 16 + lg * 4) = o;
  }
}

extern "C" void kernel_launch(void* const* d_in, const int* in_sizes, int n_in,
                              void* d_out, int out_size, void* d_ws, size_t ws_size,
                              hipStream_t stream) {
  const float* vfeat = (const float*)d_in[0];
  const float* v3d = (const float*)d_in[1];
  const float* img = (const float*)d_in[2];
  const int* vx = (const int*)d_in[3];
  const int* vy = (const int*)d_in[4];
  const float* qw = (const float*)d_in[5];
  const float* qb = (const float*)d_in[6];
  const float* kwm = (const float*)d_in[7];
  // d_in[8] = k_b: cancels in softmax
  const float* vw = (const float*)d_in[9];
  const float* vb = (const float*)d_in[10];
  const float* ow = (const float*)d_in[11];
  const float* ob = (const float*)d_in[12];
  const float* fc = (const float*)d_in[13];
  float* out = (float*)d_out;

  char* ws = (char*)d_ws;
  unsigned short* Qp = (unsigned short*)(ws);              // 256 KB
  unsigned short* K8 = (unsigned short*)(ws + 262144);     // 256 KB
  unsigned short* VTb = (unsigned short*)(ws + 524288);    // 2 MB
  unsigned short* Opb = (unsigned short*)(ws + 2621440);   // 8 MB
  float* ml = (float*)(ws + 11010048);                     // 256 KB

  kprep<<<512, 256, 0, stream>>>(vfeat, v3d, img, vx, vy, qw, qb, kwm, vw, vb,
                                 out, Qp, K8, VTb);
  kattn<<<1024, 256, 0, stream>>>(Qp, K8, VTb, Opb, ml);
  kmerge<<<256, 256, 0, stream>>>(Opb, ml, ow, ob, fc, out);
}

// Round 8
// 100.954 us; speedup vs baseline: 1.4626x; 1.3337x over previous
//
#include <hip/hip_runtime.h>

#define BB 4
#define NV 4096
#define BN (BB * NV)
#define CC 64
#define HH 376
#define WW 1240
#define HW (HH * WW)
#define LDT 72          // V/P LDS row stride (ushorts)
#define LDK 36          // K32 LDS row stride (ushorts)
#define NSPLIT 4
#define TILES 16        // 16 tiles x 64 keys = 1024 keys per split
#define QSCALE 0.1803368801111244f  // (1/8) * log2(e)

typedef __bf16 bf16x8 __attribute__((ext_vector_type(8)));
typedef __bf16 bf16x4 __attribute__((ext_vector_type(4)));
typedef float  f32x4  __attribute__((ext_vector_type(4)));

// ---------------- prep: gather + Q(3)/K(3)/V projections + passthrough ----------------
// 256 threads/block, 32 voxels/block, 8 threads per voxel; Wqk3 computed in-block.
__global__ __launch_bounds__(256) void kprep(
    const float* __restrict__ vfeat, const float* __restrict__ v3d,
    const float* __restrict__ img, const int* __restrict__ vx,
    const int* __restrict__ vy, const float* __restrict__ qw,
    const float* __restrict__ qb, const float* __restrict__ kwm,
    const float* __restrict__ vw, const float* __restrict__ vb,
    float* __restrict__ out, unsigned short* __restrict__ Qp,
    unsigned short* __restrict__ K32, unsigned short* __restrict__ VTb) {
  __shared__ float VfS[32][68];
  __shared__ float CamS[32][68];
  __shared__ float WqkS[64][4];
  __shared__ float bqkS[4];
  const int tid = threadIdx.x;
  const int vl = tid >> 3;   // voxel-local 0..31
  const int p = tid & 7;     // slice 0..7
  const int gv = blockIdx.x * 32 + vl;
  const int b = gv >> 12, n = gv & (NV - 1);
  const size_t row = (size_t)b * NV + n;

  // Wqk3[j][d] = sum_c qw[c][j]*kw[c][d]; bqk3[d] = sum_c qb[c]*kw[c][d]
  if (tid < 192) {
    int j = tid / 3, d = tid - j * 3;
    float a = 0.f;
    for (int c = 0; c < CC; ++c) a = fmaf(qw[c * CC + j], kwm[c * 3 + d], a);
    WqkS[j][d] = a;
  } else if (tid < 195) {
    int d = tid - 192;
    float a = 0.f;
    for (int c = 0; c < CC; ++c) a = fmaf(qb[c], kwm[c * 3 + d], a);
    bqkS[d] = a;
  }

  // vfeat slice: passthrough + LDS stash
  {
    const float4* vf4 = (const float4*)(vfeat + row * CC) + p * 2;
    float4* o4 = (float4*)(out + row * 128) + p * 2;
    float4* s4 = (float4*)&VfS[vl][p * 8];
#pragma unroll
    for (int i = 0; i < 2; ++i) { float4 t = vf4[i]; o4[i] = t; s4[i] = t; }
  }

  // camera gather, channels [8p, 8p+8)
  {
    int x = vx[row], y = vy[row];
    bool valid = (x >= 0) & (x < WW) & (y >= 0) & (y < HH);
    int xs = valid ? x : 0, ys = valid ? y : 0;
    const float* ib = img + ((size_t)b * CC + p * 8) * (size_t)HW + (size_t)ys * WW + xs;
#pragma unroll
    for (int i = 0; i < 8; ++i) {
      float cv = ib[(size_t)i * HW];
      CamS[vl][p * 8 + i] = valid ? cv : 0.f;
    }
  }

  // K32: raw 3d coords bf16, padded to 32
  if (p == 0) {
    float c0 = v3d[row * 3 + 0], c1 = v3d[row * 3 + 1], c2 = v3d[row * 3 + 2];
    bf16x8 kp = {(__bf16)c0, (__bf16)c1, (__bf16)c2, (__bf16)0.f,
                 (__bf16)0.f, (__bf16)0.f, (__bf16)0.f, (__bf16)0.f};
    *(bf16x8*)(K32 + row * 32) = kp;
  } else if (p < 4) {
    bf16x8 z = {(__bf16)0.f, (__bf16)0.f, (__bf16)0.f, (__bf16)0.f,
                (__bf16)0.f, (__bf16)0.f, (__bf16)0.f, (__bf16)0.f};
    *(bf16x8*)(K32 + row * 32 + p * 8) = z;
  }
  __syncthreads();

  // V projection, output channels [8p, 8p+8), store transposed bf16
  {
    f32x4 vr[16];
#pragma unroll
    for (int i = 0; i < 16; ++i) vr[i] = *(const f32x4*)&VfS[vl][i * 4];
#pragma unroll
    for (int cc = 0; cc < 8; ++cc) {
      int c = p * 8 + cc;
      const float4* w4 = (const float4*)(vw + c * CC);
      float acc = vb[c];
#pragma unroll
      for (int j = 0; j < 16; ++j) {
        float4 w = w4[j];
        acc = fmaf(vr[j][0], w.x, fmaf(vr[j][1], w.y, fmaf(vr[j][2], w.z, fmaf(vr[j][3], w.w, acc))));
      }
      ((__bf16*)VTb)[((size_t)b * CC + c) * NV + n] = (__bf16)acc;
    }
  }

  // Qp: qp3 = QSCALE*(cam @ Wqk3 + bqk3), bf16, padded to 32
  if (p == 0) {
    float q0 = bqkS[0], q1 = bqkS[1], q2 = bqkS[2];
#pragma unroll 8
    for (int j = 0; j < CC; ++j) {
      float c = CamS[vl][j];
      q0 = fmaf(c, WqkS[j][0], q0);
      q1 = fmaf(c, WqkS[j][1], q1);
      q2 = fmaf(c, WqkS[j][2], q2);
    }
    bf16x8 qp = {(__bf16)(q0 * QSCALE), (__bf16)(q1 * QSCALE), (__bf16)(q2 * QSCALE),
                 (__bf16)0.f, (__bf16)0.f, (__bf16)0.f, (__bf16)0.f, (__bf16)0.f};
    *(bf16x8*)(Qp + row * 32) = qp;
  } else if (p < 4) {
    bf16x8 z = {(__bf16)0.f, (__bf16)0.f, (__bf16)0.f, (__bf16)0.f,
                (__bf16)0.f, (__bf16)0.f, (__bf16)0.f, (__bf16)0.f};
    *(bf16x8*)(Qp + row * 32 + p * 8) = z;
  }
}

// ---------------- flash attention, split-K x4, R5 structure + fixed-M0 softmax ----------------
// grid 1024 = 4 batch x 4 splits x 64 q-chunks; 4 waves/block; 4 blocks/CU.
__global__ __launch_bounds__(256, 4) void kattn(const unsigned short* __restrict__ Qp,
                                                const unsigned short* __restrict__ K32,
                                                const unsigned short* __restrict__ VTb,
                                                unsigned short* __restrict__ Opb,
                                                float* __restrict__ ml) {
  __shared__ unsigned short Ks[2][64 * LDK];
  __shared__ unsigned short Vs[2][64 * LDT];
  __shared__ unsigned short Ps[4][16 * LDT];

  const int bid = blockIdx.x;
  const int xcd = bid & 7;
  const int idx = bid >> 3;                // 0..127
  const int combo = xcd * 2 + (idx >> 6);  // 0..15 -> (b, split)
  const int qc = idx & 63;
  const int b = combo >> 2;
  const int sp = combo & 3;
  const int q0 = qc * 64;
  const int key0 = sp * (TILES * 64);

  const int tid = threadIdx.x;
  const int wid = tid >> 6;
  const int lane = tid & 63;
  const int lq = lane & 15;
  const int lg = lane >> 4;

  const int srow = tid >> 2;         // 0..63
  const int scol = (tid & 3) * 16;   // V slot (2x uint4)
  const int kcol = (tid & 3) * 8;    // K slot (1x uint4)

  bf16x8 qf = *(const bf16x8*)(Qp + ((size_t)b * NV + q0 + wid * 16 + lq) * 32 + lg * 8);

  const f32x4 cinit = {-16.f, -16.f, -16.f, -16.f};  // fixed M0 folded into MFMA C
  float l_run = 0.f;
  f32x4 oacc[4];
#pragma unroll
  for (int t = 0; t < 4; ++t) oacc[t] = {0.f, 0.f, 0.f, 0.f};

  const unsigned short* kgb = K32 + ((size_t)b * NV) * 32;
  const unsigned short* vgb = VTb + (size_t)b * CC * NV;

  uint4 kq, vr0, vr1;
  {  // prologue: stage tile 0
    kq = *(const uint4*)(kgb + (size_t)(key0 + srow) * 32 + kcol);
    const uint4* vsrc = (const uint4*)(vgb + (size_t)srow * NV + key0 + scol);
    vr0 = vsrc[0]; vr1 = vsrc[1];
    *(uint4*)&Ks[0][srow * LDK + kcol] = kq;
    uint4* vdst = (uint4*)&Vs[0][srow * LDT + scol];
    vdst[0] = vr0; vdst[1] = vr1;
  }
  __syncthreads();

  int cur = 0;
  for (int tt = 0; tt < TILES; ++tt) {
    if (tt + 1 < TILES) {  // issue next tile's loads early
      int k0 = key0 + (tt + 1) * 64;
      kq = *(const uint4*)(kgb + (size_t)(k0 + srow) * 32 + kcol);
      const uint4* vsrc = (const uint4*)(vgb + (size_t)srow * NV + k0 + scol);
      vr0 = vsrc[0]; vr1 = vsrc[1];
    }

    // S^T = K . Q^T - 16 (log2 domain; k>=3 zero on both operands)
    f32x4 s[4];
#pragma unroll
    for (int t = 0; t < 4; ++t) {
      bf16x8 ka = *(const bf16x8*)&Ks[cur][(t * 16 + lq) * LDK + lg * 8];
      s[t] = __builtin_amdgcn_mfma_f32_16x16x32_bf16(ka, qf, cinit, 0, 0, 0);
    }

    // p = exp2(s); lane-partial l (no max tracking, no rescale ever)
#pragma unroll
    for (int t = 0; t < 4; ++t) {
      float p0 = __builtin_amdgcn_exp2f(s[t][0]);
      float p1 = __builtin_amdgcn_exp2f(s[t][1]);
      float p2 = __builtin_amdgcn_exp2f(s[t][2]);
      float p3 = __builtin_amdgcn_exp2f(s[t][3]);
      l_run += (p0 + p1) + (p2 + p3);
      bf16x4 pk;
      pk[0] = (__bf16)p0; pk[1] = (__bf16)p1; pk[2] = (__bf16)p2; pk[3] = (__bf16)p3;
      *(bf16x4*)&Ps[wid][lq * LDT + t * 16 + lg * 4] = pk;
    }

    // O += P . V
#pragma unroll
    for (int ks = 0; ks < 2; ++ks) {
      bf16x8 pa = *(const bf16x8*)&Ps[wid][lq * LDT + ks * 32 + lg * 8];
#pragma unroll
      for (int t = 0; t < 4; ++t) {
        bf16x8 vbf = *(const bf16x8*)&Vs[cur][(t * 16 + lq) * LDT + ks * 32 + lg * 8];
        oacc[t] = __builtin_amdgcn_mfma_f32_16x16x32_bf16(pa, vbf, oacc[t], 0, 0, 0);
      }
    }

    if (tt + 1 < TILES) {
      *(uint4*)&Ks[cur ^ 1][srow * LDK + kcol] = kq;
      uint4* vdst = (uint4*)&Vs[cur ^ 1][srow * LDT + scol];
      vdst[0] = vr0; vdst[1] = vr1;
    }
    __syncthreads();
    cur ^= 1;
  }

  // final l reduction across the 4 lanes sharing query lq
  l_run += __shfl_xor(l_run, 16);
  l_run += __shfl_xor(l_run, 32);

  // write unnormalized partial O (bf16) and l
  const size_t obase = (size_t)sp * BN + (size_t)b * NV + q0 + wid * 16;
#pragma unroll
  for (int r = 0; r < 4; ++r) {
    __bf16* op = (__bf16*)Opb + (obase + lg * 4 + r) * CC + lq;
#pragma unroll
    for (int t = 0; t < 4; ++t) op[t * 16] = (__bf16)oacc[t][r];
  }
  if (lg == 0) ml[obase + lq] = l_run;
}

// ---------------- merge 4 partials (plain sum) + fused epilogue ----------------
__global__ __launch_bounds__(256) void kmerge(const unsigned short* __restrict__ Opb,
                                              const float* __restrict__ ml,
                                              const float* __restrict__ ow,
                                              const float* __restrict__ ob,
                                              const float* __restrict__ fc,
                                              float* __restrict__ out) {
  __shared__ unsigned short W2s[64 * LDT];
  __shared__ float b2s[64];
  const int tid = threadIdx.x;
  const int wid = tid >> 6;
  const int lane = tid & 63;
  const int lq = lane & 15;
  const int lg = lane >> 4;

  // W2[i][j] = sum_k fc[i][k]*ow[k][j]
  {
    const int i = tid >> 2;
    const int jb = (tid & 3) * 16;
    float acc[16];
#pragma unroll
    for (int e = 0; e < 16; ++e) acc[e] = 0.f;
    for (int k = 0; k < CC; ++k) {
      float f = fc[i * CC + k];
      const float4* o4 = (const float4*)(ow + k * CC + jb);
#pragma unroll
      for (int e4 = 0; e4 < 4; ++e4) {
        float4 o = o4[e4];
        acc[e4 * 4 + 0] = fmaf(f, o.x, acc[e4 * 4 + 0]);
        acc[e4 * 4 + 1] = fmaf(f, o.y, acc[e4 * 4 + 1]);
        acc[e4 * 4 + 2] = fmaf(f, o.z, acc[e4 * 4 + 2]);
        acc[e4 * 4 + 3] = fmaf(f, o.w, acc[e4 * 4 + 3]);
      }
    }
    __bf16* wrow = (__bf16*)&W2s[i * LDT + jb];
#pragma unroll
    for (int e = 0; e < 16; ++e) wrow[e] = (__bf16)acc[e];
    if (tid < CC) {
      float a = 0.f;
      for (int k = 0; k < CC; ++k) a = fmaf(fc[tid * CC + k], ob[k], a);
      b2s[tid] = a;
    }
  }
  __syncthreads();

  const int row = blockIdx.x * 64 + wid * 16 + lq;

  float lstar = 0.f;
#pragma unroll
  for (int s = 0; s < NSPLIT; ++s) lstar += ml[(size_t)s * BN + row];

  float ctx[16];
#pragma unroll
  for (int j = 0; j < 16; ++j) ctx[j] = 0.f;
#pragma unroll
  for (int s = 0; s < NSPLIT; ++s) {
    const __bf16* oprow = (const __bf16*)Opb + ((size_t)s * BN + row) * CC;
    bf16x8 a0 = *(const bf16x8*)(oprow + lg * 8);
    bf16x8 a1 = *(const bf16x8*)(oprow + 32 + lg * 8);
#pragma unroll
    for (int j = 0; j < 8; ++j) {
      ctx[j] += (float)a0[j];
      ctx[8 + j] += (float)a1[j];
    }
  }
  float inv = 1.f / lstar;
  bf16x8 cb0, cb1;
#pragma unroll
  for (int j = 0; j < 8; ++j) {
    cb0[j] = (__bf16)(ctx[j] * inv);
    cb1[j] = (__bf16)(ctx[8 + j] * inv);
  }

  const f32x4 vzero = {0.f, 0.f, 0.f, 0.f};
  float* orow = out + (size_t)row * 128 + 64;
#pragma unroll
  for (int t2 = 0; t2 < 4; ++t2) {
    bf16x8 wa0 = *(const bf16x8*)&W2s[(t2 * 16 + lq) * LDT + lg * 8];
    bf16x8 wa1 = *(const bf16x8*)&W2s[(t2 * 16 + lq) * LDT + 32 + lg * 8];
    f32x4 r2 = vzero;
    r2 = __builtin_amdgcn_mfma_f32_16x16x32_bf16(wa0, cb0, r2, 0, 0, 0);
    r2 = __builtin_amdgcn_mfma_f32_16x16x32_bf16(wa1, cb1, r2, 0, 0, 0);
    float4 o;
    o.x = fmaxf(r2[0] + b2s[t2 * 16 + lg * 4 + 0], 0.f);
    o.y = fmaxf(r2[1] + b2s[t2 * 16 + lg * 4 + 1], 0.f);
    o.z = fmaxf(r2[2] + b2s[t2 * 16 + lg * 4 + 2], 0.f);
    o.w = fmaxf(r2[3] + b2s[t2 * 16 + lg * 4 + 3], 0.f);
    *(float4*)(orow + t2 * 16 + lg * 4) = o;
  }
}

extern "C" void kernel_launch(void* const* d_in, const int* in_sizes, int n_in,
                              void* d_out, int out_size, void* d_ws, size_t ws_size,
                              hipStream_t stream) {
  const float* vfeat = (const float*)d_in[0];
  const float* v3d = (const float*)d_in[1];
  const float* img = (const float*)d_in[2];
  const int* vx = (const int*)d_in[3];
  const int* vy = (const int*)d_in[4];
  const float* qw = (const float*)d_in[5];
  const float* qb = (const float*)d_in[6];
  const float* kwm = (const float*)d_in[7];
  // d_in[8] = k_b: cancels in softmax
  const float* vw = (const float*)d_in[9];
  const float* vb = (const float*)d_in[10];
  const float* ow = (const float*)d_in[11];
  const float* ob = (const float*)d_in[12];
  const float* fc = (const float*)d_in[13];
  float* out = (float*)d_out;

  char* ws = (char*)d_ws;
  unsigned short* Qp = (unsigned short*)(ws);              // 1 MB
  unsigned short* K32 = (unsigned short*)(ws + (1u << 20)); // 1 MB
  unsigned short* VTb = (unsigned short*)(ws + (2u << 20)); // 2 MB
  unsigned short* Opb = (unsigned short*)(ws + (4u << 20)); // 8 MB
  float* ml = (float*)(ws + (12u << 20));                   // 256 KB

  kprep<<<512, 256, 0, stream>>>(vfeat, v3d, img, vx, vy, qw, qb, kwm, vw, vb,
                                 out, Qp, K32, VTb);
  kattn<<<1024, 256, 0, stream>>>(Qp, K32, VTb, Opb, ml);
  kmerge<<<256, 256, 0, stream>>>(Opb, ml, ow, ob, fc, out);
}

// Round 9
// 98.237 us; speedup vs baseline: 1.5030x; 1.0276x over previous
//
#include <hip/hip_runtime.h>

#define BB 4
#define NV 4096
#define BN (BB * NV)
#define CC 64
#define HH 376
#define WW 1240
#define HW (HH * WW)
#define LDT 72          // V/P LDS row stride (ushorts)
#define LDK 36          // K32 LDS row stride (ushorts)
#define NSPLIT 4
#define TILES 16        // 16 tiles x 64 keys = 1024 keys per split
#define QSCALE 0.1803368801111244f  // (1/8) * log2(e)

typedef __bf16 bf16x8 __attribute__((ext_vector_type(8)));
typedef __bf16 bf16x4 __attribute__((ext_vector_type(4)));
typedef float  f32x4  __attribute__((ext_vector_type(4)));

// ---------------- prep: gather + Q(3)/K(3)/V projections + passthrough ----------------
__global__ __launch_bounds__(256) void kprep(
    const float* __restrict__ vfeat, const float* __restrict__ v3d,
    const float* __restrict__ img, const int* __restrict__ vx,
    const int* __restrict__ vy, const float* __restrict__ qw,
    const float* __restrict__ qb, const float* __restrict__ kwm,
    const float* __restrict__ vw, const float* __restrict__ vb,
    float* __restrict__ out, unsigned short* __restrict__ Qp,
    unsigned short* __restrict__ K32, unsigned short* __restrict__ VTb) {
  __shared__ float VfS[32][68];
  __shared__ float CamS[32][68];
  __shared__ float WqkS[64][4];
  __shared__ float bqkS[4];
  const int tid = threadIdx.x;
  const int vl = tid >> 3;   // voxel-local 0..31
  const int p = tid & 7;     // slice 0..7
  const int gv = blockIdx.x * 32 + vl;
  const int b = gv >> 12, n = gv & (NV - 1);
  const size_t row = (size_t)b * NV + n;

  // Wqk3[j][d] = sum_c qw[c][j]*kw[c][d]; bqk3[d] = sum_c qb[c]*kw[c][d]
  if (tid < 192) {
    int j = tid / 3, d = tid - j * 3;
    float a = 0.f;
    for (int c = 0; c < CC; ++c) a = fmaf(qw[c * CC + j], kwm[c * 3 + d], a);
    WqkS[j][d] = a;
  } else if (tid < 195) {
    int d = tid - 192;
    float a = 0.f;
    for (int c = 0; c < CC; ++c) a = fmaf(qb[c], kwm[c * 3 + d], a);
    bqkS[d] = a;
  }

  // vfeat slice: passthrough + LDS stash
  {
    const float4* vf4 = (const float4*)(vfeat + row * CC) + p * 2;
    float4* o4 = (float4*)(out + row * 128) + p * 2;
    float4* s4 = (float4*)&VfS[vl][p * 8];
#pragma unroll
    for (int i = 0; i < 2; ++i) { float4 t = vf4[i]; o4[i] = t; s4[i] = t; }
  }

  // camera gather, channels [8p, 8p+8)
  {
    int x = vx[row], y = vy[row];
    bool valid = (x >= 0) & (x < WW) & (y >= 0) & (y < HH);
    int xs = valid ? x : 0, ys = valid ? y : 0;
    const float* ib = img + ((size_t)b * CC + p * 8) * (size_t)HW + (size_t)ys * WW + xs;
#pragma unroll
    for (int i = 0; i < 8; ++i) {
      float cv = ib[(size_t)i * HW];
      CamS[vl][p * 8 + i] = valid ? cv : 0.f;
    }
  }

  // K32: raw 3d coords bf16, padded to 32
  if (p == 0) {
    float c0 = v3d[row * 3 + 0], c1 = v3d[row * 3 + 1], c2 = v3d[row * 3 + 2];
    bf16x8 kp = {(__bf16)c0, (__bf16)c1, (__bf16)c2, (__bf16)0.f,
                 (__bf16)0.f, (__bf16)0.f, (__bf16)0.f, (__bf16)0.f};
    *(bf16x8*)(K32 + row * 32) = kp;
  } else if (p < 4) {
    bf16x8 z = {(__bf16)0.f, (__bf16)0.f, (__bf16)0.f, (__bf16)0.f,
                (__bf16)0.f, (__bf16)0.f, (__bf16)0.f, (__bf16)0.f};
    *(bf16x8*)(K32 + row * 32 + p * 8) = z;
  }
  __syncthreads();

  // V projection, output channels [8p, 8p+8), store transposed bf16
  {
    f32x4 vr[16];
#pragma unroll
    for (int i = 0; i < 16; ++i) vr[i] = *(const f32x4*)&VfS[vl][i * 4];
#pragma unroll
    for (int cc = 0; cc < 8; ++cc) {
      int c = p * 8 + cc;
      const float4* w4 = (const float4*)(vw + c * CC);
      float acc = vb[c];
#pragma unroll
      for (int j = 0; j < 16; ++j) {
        float4 w = w4[j];
        acc = fmaf(vr[j][0], w.x, fmaf(vr[j][1], w.y, fmaf(vr[j][2], w.z, fmaf(vr[j][3], w.w, acc))));
      }
      ((__bf16*)VTb)[((size_t)b * CC + c) * NV + n] = (__bf16)acc;
    }
  }

  // Qp: qp3 = QSCALE*(cam @ Wqk3 + bqk3), bf16, padded to 32
  if (p == 0) {
    float q0 = bqkS[0], q1 = bqkS[1], q2 = bqkS[2];
#pragma unroll 8
    for (int j = 0; j < CC; ++j) {
      float c = CamS[vl][j];
      q0 = fmaf(c, WqkS[j][0], q0);
      q1 = fmaf(c, WqkS[j][1], q1);
      q2 = fmaf(c, WqkS[j][2], q2);
    }
    bf16x8 qp = {(__bf16)(q0 * QSCALE), (__bf16)(q1 * QSCALE), (__bf16)(q2 * QSCALE),
                 (__bf16)0.f, (__bf16)0.f, (__bf16)0.f, (__bf16)0.f, (__bf16)0.f};
    *(bf16x8*)(Qp + row * 32) = qp;
  } else if (p < 4) {
    bf16x8 z = {(__bf16)0.f, (__bf16)0.f, (__bf16)0.f, (__bf16)0.f,
                (__bf16)0.f, (__bf16)0.f, (__bf16)0.f, (__bf16)0.f};
    *(bf16x8*)(Qp + row * 32 + p * 8) = z;
  }
}

// ---------------- flash attention: QBLK=128, 32 q/wave, split-K x4, fixed-M0 ----------------
// grid 512 = 4 batch x 4 splits x 32 q-chunks; 4 waves/block; 2 blocks/CU.
// Each ka/vbf LDS read feeds TWO MFMAs (two 16-query sub-tiles held in regs).
__global__ __launch_bounds__(256, 2) void kattn(const unsigned short* __restrict__ Qp,
                                                const unsigned short* __restrict__ K32,
                                                const unsigned short* __restrict__ VTb,
                                                unsigned short* __restrict__ Opb,
                                                float* __restrict__ ml) {
  __shared__ unsigned short Ks[2][64 * LDK];
  __shared__ unsigned short Vs[2][64 * LDT];
  __shared__ unsigned short Ps[4][2][16 * LDT];

  const int bid = blockIdx.x;
  const int xcd = bid & 7;
  const int idx = bid >> 3;                // 0..63
  const int combo = xcd * 2 + (idx >> 5);  // 0..15 -> (b, split)
  const int qc = idx & 31;
  const int b = combo >> 2;
  const int sp = combo & 3;
  const int q0 = qc * 128;
  const int key0 = sp * (TILES * 64);

  const int tid = threadIdx.x;
  const int wid = tid >> 6;
  const int lane = tid & 63;
  const int lq = lane & 15;
  const int lg = lane >> 4;

  const int srow = tid >> 2;         // 0..63
  const int scol = (tid & 3) * 16;   // V slot (2x uint4)
  const int kcol = (tid & 3) * 8;    // K slot (1x uint4)

  const size_t qrow = (size_t)b * NV + q0 + wid * 32 + lq;
  bf16x8 qf0 = *(const bf16x8*)(Qp + qrow * 32 + lg * 8);
  bf16x8 qf1 = *(const bf16x8*)(Qp + (qrow + 16) * 32 + lg * 8);

  const f32x4 cinit = {-16.f, -16.f, -16.f, -16.f};  // fixed M0 folded into MFMA C
  float l0 = 0.f, l1 = 0.f;
  f32x4 oacc0[4], oacc1[4];
#pragma unroll
  for (int t = 0; t < 4; ++t) { oacc0[t] = {0.f, 0.f, 0.f, 0.f}; oacc1[t] = {0.f, 0.f, 0.f, 0.f}; }

  const unsigned short* kgb = K32 + ((size_t)b * NV) * 32;
  const unsigned short* vgb = VTb + (size_t)b * CC * NV;

  uint4 kq, vr0, vr1;
  {  // prologue: stage tile 0
    kq = *(const uint4*)(kgb + (size_t)(key0 + srow) * 32 + kcol);
    const uint4* vsrc = (const uint4*)(vgb + (size_t)srow * NV + key0 + scol);
    vr0 = vsrc[0]; vr1 = vsrc[1];
    *(uint4*)&Ks[0][srow * LDK + kcol] = kq;
    uint4* vdst = (uint4*)&Vs[0][srow * LDT + scol];
    vdst[0] = vr0; vdst[1] = vr1;
  }
  __syncthreads();

  int cur = 0;
  for (int tt = 0; tt < TILES; ++tt) {
    if (tt + 1 < TILES) {  // issue next tile's loads early
      int k0 = key0 + (tt + 1) * 64;
      kq = *(const uint4*)(kgb + (size_t)(k0 + srow) * 32 + kcol);
      const uint4* vsrc = (const uint4*)(vgb + (size_t)srow * NV + k0 + scol);
      vr0 = vsrc[0]; vr1 = vsrc[1];
    }

    // S^T = K . Q^T - 16 (log2 domain); one ka read feeds both q-subtiles
    f32x4 s0[4], s1[4];
#pragma unroll
    for (int t = 0; t < 4; ++t) {
      bf16x8 ka = *(const bf16x8*)&Ks[cur][(t * 16 + lq) * LDK + lg * 8];
      s0[t] = __builtin_amdgcn_mfma_f32_16x16x32_bf16(ka, qf0, cinit, 0, 0, 0);
      s1[t] = __builtin_amdgcn_mfma_f32_16x16x32_bf16(ka, qf1, cinit, 0, 0, 0);
    }

    // p = exp2(s); lane-partial l (no max tracking, no rescale)
#pragma unroll
    for (int t = 0; t < 4; ++t) {
      float a0 = __builtin_amdgcn_exp2f(s0[t][0]);
      float a1 = __builtin_amdgcn_exp2f(s0[t][1]);
      float a2 = __builtin_amdgcn_exp2f(s0[t][2]);
      float a3 = __builtin_amdgcn_exp2f(s0[t][3]);
      l0 += (a0 + a1) + (a2 + a3);
      bf16x4 pk0;
      pk0[0] = (__bf16)a0; pk0[1] = (__bf16)a1; pk0[2] = (__bf16)a2; pk0[3] = (__bf16)a3;
      *(bf16x4*)&Ps[wid][0][lq * LDT + t * 16 + lg * 4] = pk0;
      float c0 = __builtin_amdgcn_exp2f(s1[t][0]);
      float c1 = __builtin_amdgcn_exp2f(s1[t][1]);
      float c2 = __builtin_amdgcn_exp2f(s1[t][2]);
      float c3 = __builtin_amdgcn_exp2f(s1[t][3]);
      l1 += (c0 + c1) + (c2 + c3);
      bf16x4 pk1;
      pk1[0] = (__bf16)c0; pk1[1] = (__bf16)c1; pk1[2] = (__bf16)c2; pk1[3] = (__bf16)c3;
      *(bf16x4*)&Ps[wid][1][lq * LDT + t * 16 + lg * 4] = pk1;
    }

    // O += P . V ; one vbf read feeds both q-subtiles
#pragma unroll
    for (int ks = 0; ks < 2; ++ks) {
      bf16x8 pa0 = *(const bf16x8*)&Ps[wid][0][lq * LDT + ks * 32 + lg * 8];
      bf16x8 pa1 = *(const bf16x8*)&Ps[wid][1][lq * LDT + ks * 32 + lg * 8];
#pragma unroll
      for (int t = 0; t < 4; ++t) {
        bf16x8 vbf = *(const bf16x8*)&Vs[cur][(t * 16 + lq) * LDT + ks * 32 + lg * 8];
        oacc0[t] = __builtin_amdgcn_mfma_f32_16x16x32_bf16(pa0, vbf, oacc0[t], 0, 0, 0);
        oacc1[t] = __builtin_amdgcn_mfma_f32_16x16x32_bf16(pa1, vbf, oacc1[t], 0, 0, 0);
      }
    }

    if (tt + 1 < TILES) {
      *(uint4*)&Ks[cur ^ 1][srow * LDK + kcol] = kq;
      uint4* vdst = (uint4*)&Vs[cur ^ 1][srow * LDT + scol];
      vdst[0] = vr0; vdst[1] = vr1;
    }
    __syncthreads();
    cur ^= 1;
  }

  // final l reduction across the 4 lanes sharing query lq
  l0 += __shfl_xor(l0, 16); l0 += __shfl_xor(l0, 32);
  l1 += __shfl_xor(l1, 16); l1 += __shfl_xor(l1, 32);

  // write unnormalized partial O (bf16) and l, both q-subtiles
  const size_t obase = (size_t)sp * BN + (size_t)b * NV + q0 + wid * 32;
#pragma unroll
  for (int r = 0; r < 4; ++r) {
    __bf16* op0 = (__bf16*)Opb + (obase + lg * 4 + r) * CC + lq;
    __bf16* op1 = (__bf16*)Opb + (obase + 16 + lg * 4 + r) * CC + lq;
#pragma unroll
    for (int t = 0; t < 4; ++t) {
      op0[t * 16] = (__bf16)oacc0[t][r];
      op1[t * 16] = (__bf16)oacc1[t][r];
    }
  }
  if (lg == 0) {
    ml[obase + lq] = l0;
    ml[obase + 16 + lq] = l1;
  }
}

// ---------------- merge 4 partials (plain sum) + fused epilogue ----------------
__global__ __launch_bounds__(256) void kmerge(const unsigned short* __restrict__ Opb,
                                              const float* __restrict__ ml,
                                              const float* __restrict__ ow,
                                              const float* __restrict__ ob,
                                              const float* __restrict__ fc,
                                              float* __restrict__ out) {
  __shared__ unsigned short W2s[64 * LDT];
  __shared__ float b2s[64];
  const int tid = threadIdx.x;
  const int wid = tid >> 6;
  const int lane = tid & 63;
  const int lq = lane & 15;
  const int lg = lane >> 4;

  // W2[i][j] = sum_k fc[i][k]*ow[k][j]
  {
    const int i = tid >> 2;
    const int jb = (tid & 3) * 16;
    float acc[16];
#pragma unroll
    for (int e = 0; e < 16; ++e) acc[e] = 0.f;
    for (int k = 0; k < CC; ++k) {
      float f = fc[i * CC + k];
      const float4* o4 = (const float4*)(ow + k * CC + jb);
#pragma unroll
      for (int e4 = 0; e4 < 4; ++e4) {
        float4 o = o4[e4];
        acc[e4 * 4 + 0] = fmaf(f, o.x, acc[e4 * 4 + 0]);
        acc[e4 * 4 + 1] = fmaf(f, o.y, acc[e4 * 4 + 1]);
        acc[e4 * 4 + 2] = fmaf(f, o.z, acc[e4 * 4 + 2]);
        acc[e4 * 4 + 3] = fmaf(f, o.w, acc[e4 * 4 + 3]);
      }
    }
    __bf16* wrow = (__bf16*)&W2s[i * LDT + jb];
#pragma unroll
    for (int e = 0; e < 16; ++e) wrow[e] = (__bf16)acc[e];
    if (tid < CC) {
      float a = 0.f;
      for (int k = 0; k < CC; ++k) a = fmaf(fc[tid * CC + k], ob[k], a);
      b2s[tid] = a;
    }
  }
  __syncthreads();

  const int row = blockIdx.x * 64 + wid * 16 + lq;

  float lstar = 0.f;
#pragma unroll
  for (int s = 0; s < NSPLIT; ++s) lstar += ml[(size_t)s * BN + row];

  float ctx[16];
#pragma unroll
  for (int j = 0; j < 16; ++j) ctx[j] = 0.f;
#pragma unroll
  for (int s = 0; s < NSPLIT; ++s) {
    const __bf16* oprow = (const __bf16*)Opb + ((size_t)s * BN + row) * CC;
    bf16x8 a0 = *(const bf16x8*)(oprow + lg * 8);
    bf16x8 a1 = *(const bf16x8*)(oprow + 32 + lg * 8);
#pragma unroll
    for (int j = 0; j < 8; ++j) {
      ctx[j] += (float)a0[j];
      ctx[8 + j] += (float)a1[j];
    }
  }
  float inv = 1.f / lstar;
  bf16x8 cb0, cb1;
#pragma unroll
  for (int j = 0; j < 8; ++j) {
    cb0[j] = (__bf16)(ctx[j] * inv);
    cb1[j] = (__bf16)(ctx[8 + j] * inv);
  }

  const f32x4 vzero = {0.f, 0.f, 0.f, 0.f};
  float* orow = out + (size_t)row * 128 + 64;
#pragma unroll
  for (int t2 = 0; t2 < 4; ++t2) {
    bf16x8 wa0 = *(const bf16x8*)&W2s[(t2 * 16 + lq) * LDT + lg * 8];
    bf16x8 wa1 = *(const bf16x8*)&W2s[(t2 * 16 + lq) * LDT + 32 + lg * 8];
    f32x4 r2 = vzero;
    r2 = __builtin_amdgcn_mfma_f32_16x16x32_bf16(wa0, cb0, r2, 0, 0, 0);
    r2 = __builtin_amdgcn_mfma_f32_16x16x32_bf16(wa1, cb1, r2, 0, 0, 0);
    float4 o;
    o.x = fmaxf(r2[0] + b2s[t2 * 16 + lg * 4 + 0], 0.f);
    o.y = fmaxf(r2[1] + b2s[t2 * 16 + lg * 4 + 1], 0.f);
    o.z = fmaxf(r2[2] + b2s[t2 * 16 + lg * 4 + 2], 0.f);
    o.w = fmaxf(r2[3] + b2s[t2 * 16 + lg * 4 + 3], 0.f);
    *(float4*)(orow + t2 * 16 + lg * 4) = o;
  }
}

extern "C" void kernel_launch(void* const* d_in, const int* in_sizes, int n_in,
                              void* d_out, int out_size, void* d_ws, size_t ws_size,
                              hipStream_t stream) {
  const float* vfeat = (const float*)d_in[0];
  const float* v3d = (const float*)d_in[1];
  const float* img = (const float*)d_in[2];
  const int* vx = (const int*)d_in[3];
  const int* vy = (const int*)d_in[4];
  const float* qw = (const float*)d_in[5];
  const float* qb = (const float*)d_in[6];
  const float* kwm = (const float*)d_in[7];
  // d_in[8] = k_b: cancels in softmax
  const float* vw = (const float*)d_in[9];
  const float* vb = (const float*)d_in[10];
  const float* ow = (const float*)d_in[11];
  const float* ob = (const float*)d_in[12];
  const float* fc = (const float*)d_in[13];
  float* out = (float*)d_out;

  char* ws = (char*)d_ws;
  unsigned short* Qp = (unsigned short*)(ws);               // 1 MB
  unsigned short* K32 = (unsigned short*)(ws + (1u << 20)); // 1 MB
  unsigned short* VTb = (unsigned short*)(ws + (2u << 20)); // 2 MB
  unsigned short* Opb = (unsigned short*)(ws + (4u << 20)); // 8 MB
  float* ml = (float*)(ws + (12u << 20));                   // 256 KB

  kprep<<<512, 256, 0, stream>>>(vfeat, v3d, img, vx, vy, qw, qb, kwm, vw, vb,
                                 out, Qp, K32, VTb);
  kattn<<<512, 256, 0, stream>>>(Qp, K32, VTb, Opb, ml);
  kmerge<<<256, 256, 0, stream>>>(Opb, ml, ow, ob, fc, out);
}